// Round 5
// baseline (97.377 us; speedup 1.0000x reference)
//
#include <hip/hip_runtime.h>

// DivEncLayer via MFMA — ILP-focused: one wave owns a whole q-tile (4 q's),
// 4 independent MFMA+finish chains per 32-row group, zero barriers.
// Per (b,q): h = elu(x[b,q*8:+8]@W1[q] + b1[q]); LN(h); out = h@W2[q]+b2[q].
// B=16384, Q=128, S=8, U=32.
//
// One v_mfma_f32_32x32x16_bf16 per (32-row group, q):
//   A lanes 0-31  (k=0..7):  whi[u][k]   = bf16(W1[q][k][u])
//   A lanes 32-63 (k=8..15): wlo[u][k-8] = bf16(W1 - whi)     (hi/lo split)
//   B: every lane loads row b0+(ln&31); same xfrag in both k-halves
//   D layout: col=lane&31 -> b, row r -> u=(r&3)+8*(r>>2)+4*(lane>>5)  [HW-verified]
// b1 added post-MFMA (fp32, from LDS broadcast). LN+Dense2 folded:
//   out = rsqrt(var+eps)*(dot(e,g2) - mu*G) + C;  g2=gamma*W2, G=sum g2,
//   C=sum(beta*W2)+b2.
// Wave computes res[4] -> direct float4 store per row (write-exact pattern).
// Grid (32,32): wave w handles row-groups (bx*4+w) + i*128, i=0..3, qt=by.
// x prefetched one group ahead (8 float4 regs).

typedef __attribute__((ext_vector_type(8))) short short8;    // 8 bf16
typedef __attribute__((ext_vector_type(16))) float f32x16;

__device__ __forceinline__ short fbits(__bf16 b) { return __builtin_bit_cast(short, b); }

__device__ __forceinline__ float elu1(float v) {
    return v > 0.f ? v : __expf(v) - 1.f;
}

__global__ __launch_bounds__(256, 3) void divenc_mfma(
    const float* __restrict__ x,      // (16384, 1024)
    const float* __restrict__ W1,     // (128, 8, 32)
    const float* __restrict__ b1,     // (128, 32)
    const float* __restrict__ gamma,  // (128, 32)
    const float* __restrict__ beta,   // (128, 32)
    const float* __restrict__ W2,     // (128, 32)
    const float* __restrict__ b2,     // (128,)
    float* __restrict__ out)          // (16384, 128)
{
    __shared__ float lp[4][32][2];    // [qq][u][{b1,g2}] — all waves write same data

    const int tid  = threadIdx.x;
    const int w    = tid >> 6;
    const int ln   = tid & 63;
    const int u    = ln & 31;
    const int half = ln >> 5;
    const int qt   = blockIdx.y;              // 0..31
    const int wg   = blockIdx.x * 4 + w;      // row-group 0..127; iter stride 128

    // ---- per-wave setup: A-frags, params ----
    short8 wfrag[4];
    float Gv[4], Cv[4];
    #pragma unroll
    for (int qq = 0; qq < 4; ++qq) {
        const int q = qt * 4 + qq;
        #pragma unroll
        for (int j = 0; j < 8; ++j) {
            float f  = W1[q * 256 + j * 32 + u];
            __bf16 h = (__bf16)f;
            wfrag[qq][j] = half ? fbits((__bf16)(f - (float)h)) : fbits(h);
        }
        float w2 = W2[q * 32 + u];
        float g2 = gamma[q * 32 + u] * w2;
        if (half == 0) {
            lp[qq][u][0] = b1[q * 32 + u];
            lp[qq][u][1] = g2;
        }
        float gs = g2, cs = beta[q * 32 + u] * w2;
        #pragma unroll
        for (int m = 1; m < 32; m <<= 1) {   // halves duplicate u -> 5 steps suffice
            gs += __shfl_xor(gs, m);
            cs += __shfl_xor(cs, m);
        }
        Gv[qq] = gs;
        Cv[qq] = cs + b2[q];
    }
    // same-wave DS ordering makes lp visible to this wave; other waves wrote
    // identical bytes, so cross-wave timing is irrelevant. No barrier.

    const float* xq = x + qt * 32;   // this q-tile's 32 columns

    // prime group 0: lane reads 32 contiguous floats of row (wg*32+u)
    float4 cx[8];
    {
        const float4* p = (const float4*)(xq + (size_t)(wg * 32 + u) * 1024);
        #pragma unroll
        for (int t = 0; t < 8; ++t) cx[t] = p[t];
    }

    #pragma unroll 1
    for (int i = 0; i < 4; ++i) {
        const int b0 = (wg + i * 128) * 32;

        // prefetch next group (last iter re-reads current; L2-hot, discarded)
        const int gn = (i < 3) ? wg + (i + 1) * 128 : wg + i * 128;
        const float4* pn = (const float4*)(xq + (size_t)(gn * 32 + u) * 1024);
        float4 nx[8];
        #pragma unroll
        for (int t = 0; t < 8; ++t) nx[t] = pn[t];

        float resv[4];
        #pragma unroll
        for (int qq = 0; qq < 4; ++qq) {
            float xf8[8] = {cx[2*qq].x,   cx[2*qq].y,   cx[2*qq].z,   cx[2*qq].w,
                            cx[2*qq+1].x, cx[2*qq+1].y, cx[2*qq+1].z, cx[2*qq+1].w};
            short8 xfrag;
            #pragma unroll
            for (int j = 0; j < 8; ++j) xfrag[j] = fbits((__bf16)xf8[j]);

            f32x16 z = {};
            f32x16 acc = __builtin_amdgcn_mfma_f32_32x32x16_bf16(wfrag[qq], xfrag, z, 0, 0, 0);

            // finish: e = elu(acc + b1); reduce sum/ss/dot over this half's 16 u's
            float sum = 0.f, ss = 0.f, dot = 0.f;
            #pragma unroll
            for (int c = 0; c < 4; ++c) {
                const int ub = 4 * half + 8 * c;        // r=4c+j -> u = ub+j
                float4 bg0 = *(const float4*)&lp[qq][ub][0];      // b1/g2 for u=ub,ub+1
                float4 bg1 = *(const float4*)&lp[qq][ub + 2][0];  // b1/g2 for u=ub+2,ub+3
                float e0 = elu1(acc[4*c+0] + bg0.x);
                float e1 = elu1(acc[4*c+1] + bg0.z);
                float e2 = elu1(acc[4*c+2] + bg1.x);
                float e3 = elu1(acc[4*c+3] + bg1.z);
                sum += (e0 + e1) + (e2 + e3);
                ss  = fmaf(e0, e0, fmaf(e1, e1, fmaf(e2, e2, fmaf(e3, e3, ss))));
                dot = fmaf(e0, bg0.y, fmaf(e1, bg0.w, fmaf(e2, bg1.y, fmaf(e3, bg1.w, dot))));
            }
            sum += __shfl_xor(sum, 32);
            ss  += __shfl_xor(ss, 32);
            dot += __shfl_xor(dot, 32);
            float mu  = sum * 0.03125f;
            float var = fmaf(-mu, mu, ss * 0.03125f);
            float inv = rsqrtf(var + 1e-3f);
            resv[qq] = fmaf(inv, fmaf(-mu, Gv[qq], dot), Cv[qq]);
        }

        // direct float4 store: lane u covers row b0+u, cols qt*4..+3
        if (half == 0) {
            float4 o = {resv[0], resv[1], resv[2], resv[3]};
            *(float4*)(out + (size_t)(b0 + u) * 128 + qt * 4) = o;
        }

        #pragma unroll
        for (int t = 0; t < 8; ++t) cx[t] = nx[t];
    }
}

extern "C" void kernel_launch(void* const* d_in, const int* in_sizes, int n_in,
                              void* d_out, int out_size, void* d_ws, size_t ws_size,
                              hipStream_t stream) {
    const float* x     = (const float*)d_in[0];
    const float* W1    = (const float*)d_in[1];
    const float* b1    = (const float*)d_in[2];
    const float* gamma = (const float*)d_in[3];
    const float* beta  = (const float*)d_in[4];
    const float* W2    = (const float*)d_in[5];
    const float* b2    = (const float*)d_in[6];
    float* out = (float*)d_out;

    dim3 grid(32, 32);   // (4-wave row-group clusters, q-tiles)
    divenc_mfma<<<grid, 256, 0, stream>>>(x, W1, b1, gamma, beta, W2, b2, out);
}

// Round 6
// 29.863 us; speedup vs baseline: 3.2608x; 3.2608x over previous
//
#include <hip/hip_runtime.h>

// DivEncLayer via MFMA — round-2 skeleton + packed hi/lo A-frag, no shuffles.
// Per (b,q): h = elu(x[b,q*8:+8]@W1[q] + b1[q]); LN(h); out = h@W2[q]+b2[q].
// B=16384, Q=128, S=8, U=32.
//
// v_mfma_f32_32x32x16_bf16 operand mapping (validated rounds 2-5):
//   A: lane l, reg j -> A[l&31][j + 8*(l>>5)]
//   B: lane l, reg j -> B[j + 8*(l>>5)][l&31]
//   D: lane l, reg r -> row u=(r&3)+8*(r>>2)+4*(l>>5), col b=l&31
// Packed A-frag: lanes<32 = bf16(W1^T) (k=0..7), lanes>=32 = bf16(W1-hi) (k=8..15).
// B duplicates each row across lane-halves (loads addressed by u=ln&31), so
// D = (whi+wlo)*xhi + C-in, C-in = b1 (fp32 exact). x is bf16-hi only.
// LN+Dense2 folded: out = rsqrt(var+eps)*(dot(e,g2) - mu*G) + C,
//   g2=gamma*W2, G=sum g2, C=sum(beta*W2)+b2.
// Block = 4 waves = 4 consecutive q (wave w owns q=qt*4+w). 8 iters x 64 rows
// = 512 contiguous rows per block. Output gathered in padded LDS (stride 5),
// one float4 store per row (write-exact ~8MB, proven round 2/4).

typedef __attribute__((ext_vector_type(8))) short short8;    // 8 bf16
typedef __attribute__((ext_vector_type(16))) float f32x16;

__device__ __forceinline__ short fbits(__bf16 b) { return __builtin_bit_cast(short, b); }

__device__ __forceinline__ float elu1(float v) {
    return v > 0.f ? v : __expf(v) - 1.f;
}

__global__ __launch_bounds__(256, 4) void divenc_mfma(
    const float* __restrict__ x,      // (16384, 1024)
    const float* __restrict__ W1,     // (128, 8, 32)
    const float* __restrict__ b1,     // (128, 32)
    const float* __restrict__ gamma,  // (128, 32)
    const float* __restrict__ beta,   // (128, 32)
    const float* __restrict__ W2,     // (128, 32)
    const float* __restrict__ b2,     // (128,)
    float* __restrict__ out)          // (16384, 128)
{
    __shared__ float lout[2][64 * 5];  // [buf][row*5 + w], padded stride 5

    const int tid  = threadIdx.x;
    const int w    = tid >> 6;
    const int ln   = tid & 63;
    const int u    = ln & 31;
    const int half = ln >> 5;
    const int qt   = blockIdx.y;      // 0..31
    const int q    = qt * 4 + w;
    const int bx   = blockIdx.x;      // 0..31; block covers rows bx*512..+511

    // ---- A-frag: lanes<32 = whi (k=0..7), lanes>=32 = wlo (k=8..15) ----
    short8 wfrag;
    #pragma unroll
    for (int j = 0; j < 8; ++j) {
        float f  = W1[q * 256 + j * 32 + u];
        __bf16 h = (__bf16)f;
        wfrag[j] = half ? fbits((__bf16)(f - (float)h)) : fbits(h);
    }

    // ---- params: biasr (MFMA C-in) + g2r in regs, vector loads ----
    // reg r=4c+j -> u0 = 4*half + 8*c + j (4 contiguous float4 chunks per lane)
    f32x16 biasr, g2r;
    float G, C;
    {
        float gs = 0.f, cs = 0.f;
        #pragma unroll
        for (int c = 0; c < 4; ++c) {
            const int ub = q * 32 + 4 * half + 8 * c;
            float4 b1v = *(const float4*)&b1[ub];
            float4 gav = *(const float4*)&gamma[ub];
            float4 w2v = *(const float4*)&W2[ub];
            float4 bev = *(const float4*)&beta[ub];
            #pragma unroll
            for (int j = 0; j < 4; ++j) {
                float g2 = ((const float*)&gav)[j] * ((const float*)&w2v)[j];
                biasr[4 * c + j] = ((const float*)&b1v)[j];
                g2r[4 * c + j]   = g2;
                gs += g2;
                cs += ((const float*)&bev)[j] * ((const float*)&w2v)[j];
            }
        }
        gs += __shfl_xor(gs, 32);   // halves hold complementary u-sets
        cs += __shfl_xor(cs, 32);
        G = gs;
        C = cs + b2[q];
    }

    const float* xq = x + q * 8;

    // prime iter 0: tile0 = rows b0+u, tile1 = rows b0+32+u (dup across halves)
    float4 c00, c01, c10, c11;
    {
        const float* p0 = xq + (size_t)(bx * 512 + u) * 1024;
        const float* p1 = xq + (size_t)(bx * 512 + 32 + u) * 1024;
        c00 = ((const float4*)p0)[0]; c01 = ((const float4*)p0)[1];
        c10 = ((const float4*)p1)[0]; c11 = ((const float4*)p1)[1];
    }

    #pragma unroll 1
    for (int it = 0; it < 8; ++it) {
        const int b0 = bx * 512 + it * 64;

        // prefetch next iter (last re-reads current; L2-hot, discarded)
        const int bn = (it < 7) ? b0 + 64 : b0;
        const float* pn0 = xq + (size_t)(bn + u) * 1024;
        const float* pn1 = xq + (size_t)(bn + 32 + u) * 1024;
        float4 n00 = ((const float4*)pn0)[0], n01 = ((const float4*)pn0)[1];
        float4 n10 = ((const float4*)pn1)[0], n11 = ((const float4*)pn1)[1];

        // bf16 convert (hi only; W1 lo-term carries the correction)
        float xf0[8] = {c00.x, c00.y, c00.z, c00.w, c01.x, c01.y, c01.z, c01.w};
        float xf1[8] = {c10.x, c10.y, c10.z, c10.w, c11.x, c11.y, c11.z, c11.w};
        short8 xa, xb;
        #pragma unroll
        for (int j = 0; j < 8; ++j) {
            xa[j] = fbits((__bf16)xf0[j]);
            xb[j] = fbits((__bf16)xf1[j]);
        }

        // two independent MFMA chains, C-in = b1
        f32x16 acc0 = __builtin_amdgcn_mfma_f32_32x32x16_bf16(wfrag, xa, biasr, 0, 0, 0);
        f32x16 acc1 = __builtin_amdgcn_mfma_f32_32x32x16_bf16(wfrag, xb, biasr, 0, 0, 0);

        // ---- finish both tiles: e=elu(acc); reduce sum/ss/dot over u ----
        float res0, res1;
        {
            float sum = 0.f, ss = 0.f, dot = 0.f;
            #pragma unroll
            for (int r = 0; r < 16; ++r) {
                float e = elu1(acc0[r]);
                sum += e;
                ss  = fmaf(e, e, ss);
                dot = fmaf(e, g2r[r], dot);
            }
            sum += __shfl_xor(sum, 32);
            ss  += __shfl_xor(ss, 32);
            dot += __shfl_xor(dot, 32);
            float mu  = sum * 0.03125f;
            float var = fmaf(-mu, mu, ss * 0.03125f);
            float inv = rsqrtf(var + 1e-3f);
            res0 = fmaf(inv, fmaf(-mu, G, dot), C);
        }
        {
            float sum = 0.f, ss = 0.f, dot = 0.f;
            #pragma unroll
            for (int r = 0; r < 16; ++r) {
                float e = elu1(acc1[r]);
                sum += e;
                ss  = fmaf(e, e, ss);
                dot = fmaf(e, g2r[r], dot);
            }
            sum += __shfl_xor(sum, 32);
            ss  += __shfl_xor(ss, 32);
            dot += __shfl_xor(dot, 32);
            float mu  = sum * 0.03125f;
            float var = fmaf(-mu, mu, ss * 0.03125f);
            float inv = rsqrtf(var + 1e-3f);
            res1 = fmaf(inv, fmaf(-mu, G, dot), C);
        }

        // ---- gather 4 q's per row in LDS, one float4 store per row ----
        if (half == 0) {
            lout[it & 1][u * 5 + w]        = res0;   // row b0+u
            lout[it & 1][(u + 32) * 5 + w] = res1;   // row b0+32+u
        }
        __syncthreads();

        if (tid < 64) {
            const float* lb = lout[it & 1];
            float4 o;
            o.x = lb[tid * 5 + 0];
            o.y = lb[tid * 5 + 1];
            o.z = lb[tid * 5 + 2];
            o.w = lb[tid * 5 + 3];
            *(float4*)(out + (size_t)(b0 + tid) * 128 + qt * 4) = o;
        }

        c00 = n00; c01 = n01; c10 = n10; c11 = n11;
    }
}

extern "C" void kernel_launch(void* const* d_in, const int* in_sizes, int n_in,
                              void* d_out, int out_size, void* d_ws, size_t ws_size,
                              hipStream_t stream) {
    const float* x     = (const float*)d_in[0];
    const float* W1    = (const float*)d_in[1];
    const float* b1    = (const float*)d_in[2];
    const float* gamma = (const float*)d_in[3];
    const float* beta  = (const float*)d_in[4];
    const float* W2    = (const float*)d_in[5];
    const float* b2    = (const float*)d_in[6];
    float* out = (float*)d_out;

    dim3 grid(32, 32);   // (512-row bands, q-tiles of 4)
    divenc_mfma<<<grid, 256, 0, stream>>>(x, W1, b1, gamma, beta, W2, b2, out);
}